// Round 3
// baseline (810.798 us; speedup 1.0000x reference)
//
#include <hip/hip_runtime.h>
#include <hip/hip_bf16.h>
#include <type_traits>

using bf16 = __hip_bfloat16;
typedef __bf16 bf16x8 __attribute__((ext_vector_type(8)));
typedef float f32x4 __attribute__((ext_vector_type(4)));

static constexpr int TOKENS = 4 * 128 * 128;  // 65536
#define SCALE_F 0.11180339887498949f          // 1/sqrt(64+16)
#define EPS_F 1e-6f

__device__ __forceinline__ float b2f(bf16 v) { return __bfloat162float(v); }
__device__ __forceinline__ float u2f(unsigned short u) {
  union { unsigned int i; float f; } c; c.i = (unsigned int)u << 16; return c.f;
}
__device__ __forceinline__ unsigned short f2u(float f) {
  bf16 h = __float2bfloat16(f); return *reinterpret_cast<unsigned short*>(&h);
}
// load 8 f32, round to 8 bf16 packed in an int4
__device__ __forceinline__ int4 cvt8(const float* p) {
  float4 a = ((const float4*)p)[0], b = ((const float4*)p)[1];
  union { int4 i4; unsigned short s[8]; } u;
  u.s[0] = f2u(a.x); u.s[1] = f2u(a.y); u.s[2] = f2u(a.z); u.s[3] = f2u(a.w);
  u.s[4] = f2u(b.x); u.s[5] = f2u(b.y); u.s[6] = f2u(b.z); u.s[7] = f2u(b.w);
  return u.i4;
}

// ---------------- weight transpose + f32->bf16: out[N][K] = in[K][N] ------
__global__ void transpose_k(const float* __restrict__ in, bf16* __restrict__ out,
                            int K, int N) {
  int i = blockIdx.x * 256 + threadIdx.x;
  if (i >= K * N) return;
  int k = i / N, n = i - k * N;
  out[(size_t)n * K + k] = __float2bfloat16(in[i]);
}

// ---------------- GEMM: C[M,N] = A[M,K] @ Wt[N,K]^T + bias ----------------
// A f32 (device inputs) or bf16 (workspace); Wt bf16; f32 MFMA accum.
// C bf16 (workspace) or f32 (d_out). BM=BN=64, BK=32, 4 waves, 32x32/wave.
template <typename TA, typename TC>
__global__ __launch_bounds__(256) void gemm_bias_k(
    const TA* __restrict__ A, const bf16* __restrict__ Wt,
    const float* __restrict__ bias, TC* __restrict__ C,
    int M, int N, int K) {
  constexpr int BK = 32;
  __shared__ __align__(16) bf16 sA[64 * BK];
  __shared__ __align__(16) bf16 sB[64 * BK];
  const int bm = blockIdx.y * 64, bn = blockIdx.x * 64;
  const int t = threadIdx.x, lane = t & 63, wave = t >> 6;
  const int wr = wave >> 1, wc = wave & 1;
  f32x4 acc[2][2] = {};

  char* sAb = (char*)sA;
  char* sBb = (char*)sB;
  const int lrow = t >> 2;              // 0..63
  const int lke = (t & 3) * 8;          // element offset in row
  // XOR-swizzle 16B chunks within a 64B row: byte ^= (row&3)<<4 (both sides)
  const int sto = lrow * 64 + (((t & 3) * 16) ^ ((lrow & 3) << 4));
  const int kgb = (lane >> 4) * 16;     // k-group byte offset for fragments

  for (int k0 = 0; k0 < K; k0 += BK) {
    int4 av, bv;
    if constexpr (std::is_same<TA, float>::value) {
      av = cvt8(A + (size_t)(bm + lrow) * K + (k0 + lke));
    } else {
      av = *(const int4*)(A + (size_t)(bm + lrow) * K + (k0 + lke));
    }
    bv = *(const int4*)(Wt + (size_t)(bn + lrow) * K + (k0 + lke));
    *(int4*)(sAb + sto) = av;
    *(int4*)(sBb + sto) = bv;
    __syncthreads();
    bf16x8 af[2], bfr[2];
#pragma unroll
    for (int i = 0; i < 2; ++i) {
      int ar = wr * 32 + i * 16 + (lane & 15);
      int br = wc * 32 + i * 16 + (lane & 15);
      af[i]  = *(const bf16x8*)(sAb + ar * 64 + (kgb ^ ((ar & 3) << 4)));
      bfr[i] = *(const bf16x8*)(sBb + br * 64 + (kgb ^ ((br & 3) << 4)));
    }
#pragma unroll
    for (int i = 0; i < 2; ++i)
#pragma unroll
      for (int j = 0; j < 2; ++j)
        acc[i][j] = __builtin_amdgcn_mfma_f32_16x16x32_bf16(af[i], bfr[j], acc[i][j], 0, 0, 0);
    __syncthreads();
  }
  // epilogue: D col = lane&15, row = (lane>>4)*4 + r  [guide-verified layout]
#pragma unroll
  for (int i = 0; i < 2; ++i)
#pragma unroll
    for (int j = 0; j < 2; ++j) {
      int col = bn + wc * 32 + j * 16 + (lane & 15);
      float bv = bias[col];
      int rbase = bm + wr * 32 + i * 16 + ((lane >> 4) << 2);
#pragma unroll
      for (int r = 0; r < 4; ++r) {
        float val = acc[i][j][r] + bv;
        if constexpr (std::is_same<TC, float>::value)
          C[(size_t)(rbase + r) * N + col] = val;
        else
          C[(size_t)(rbase + r) * N + col] = __float2bfloat16(val);
      }
    }
}

// ---------------- RMSNorm (in-place bf16, f32 gain, 4 elems/thread) -------
__global__ void rmsnorm_k(bf16* __restrict__ x, const float* __restrict__ g,
                          int width) {
  const int t = threadIdx.x;
  bf16* p = x + (size_t)blockIdx.x * width;
  ushort4 v = ((const ushort4*)p)[t];
  float f0 = u2f(v.x), f1 = u2f(v.y), f2 = u2f(v.z), f3 = u2f(v.w);
  float s = f0 * f0 + f1 * f1 + f2 * f2 + f3 * f3;
#pragma unroll
  for (int o = 32; o > 0; o >>= 1) s += __shfl_down(s, o);
  __shared__ float part[4];
  __shared__ float rsh;
  const int nw = blockDim.x >> 6;
  if ((t & 63) == 0) part[t >> 6] = s;
  __syncthreads();
  if (t == 0) {
    float tot = 0.f;
    for (int i = 0; i < nw; ++i) tot += part[i];
    rsh = rsqrtf(tot / (float)width + EPS_F);
  }
  __syncthreads();
  float r = rsh;
  float4 gv = ((const float4*)g)[t];
  ushort4 o;
  o.x = f2u(f0 * r * gv.x);
  o.y = f2u(f1 * r * gv.y);
  o.z = f2u(f2 * r * gv.z);
  o.w = f2u(f3 * r * gv.w);
  ((ushort4*)p)[t] = o;
}

// ---------------- windowed attention: one block per (window, head) --------
// token(b,wy,wx,n): y=(wy*8+(n>>3)+4)&127, x=(wx*8+(n&7)+4)&127 (shift roll)
__global__ __launch_bounds__(256) void attn_k(
    const bf16* __restrict__ fqk, const bf16* __restrict__ cqk,
    const bf16* __restrict__ fv, const float* __restrict__ pos,
    bf16* __restrict__ aout) {
  __shared__ __align__(16) bf16 sQ[64][72], sK[64][72], sV[64][72];  // +8 pad
  __shared__ __align__(16) bf16 sCQ[64][24], sCK[64][24];
  __shared__ float sS[64][66];
  __shared__ float sPos[15][15];
  const int t = threadIdx.x;
  const int head = blockIdx.x & 7;
  const int wid = blockIdx.x >> 3;
  const int wx = wid & 15, wy = (wid >> 4) & 15, b = wid >> 8;

  for (int i = t; i < 225; i += 256) sPos[i / 15][i % 15] = pos[i];
  {
    const int n = t >> 2, dc = (t & 3) * 16;
    const int y = ((wy << 3) + (n >> 3) + 4) & 127;
    const int x = ((wx << 3) + (n & 7) + 4) & 127;
    const size_t tok = ((size_t)b << 14) | (y << 7) | x;
    const int4* q0 = (const int4*)(fqk + tok * 1024 + head * 64 + dc);
    ((int4*)&sQ[n][dc])[0] = q0[0];
    ((int4*)&sQ[n][dc])[1] = q0[1];
    const int4* k0 = (const int4*)(fqk + tok * 1024 + 512 + head * 64 + dc);
    ((int4*)&sK[n][dc])[0] = k0[0];
    ((int4*)&sK[n][dc])[1] = k0[1];
    const int4* v0 = (const int4*)(fv + tok * 512 + head * 64 + dc);
    ((int4*)&sV[n][dc])[0] = v0[0];
    ((int4*)&sV[n][dc])[1] = v0[1];
  }
  if (t < 128) {
    const int n = t & 63;
    const bool isk = t >= 64;
    const int y = ((wy << 3) + (n >> 3) + 4) & 127;
    const int x = ((wx << 3) + (n & 7) + 4) & 127;
    const size_t tok = ((size_t)b << 14) | (y << 7) | x;
    const int4* c0 = (const int4*)(cqk + tok * 256 + (isk ? 128 : 0) + head * 16);
    bf16* dst = isk ? &sCK[n][0] : &sCQ[n][0];
    ((int4*)dst)[0] = c0[0];
    ((int4*)dst)[1] = c0[1];
  }
  __syncthreads();

  // scores: thread computes 4x4 tile of S
  const int qb = (t >> 4) << 2, kb = (t & 15) << 2;
  float a[4][4] = {};
  for (int d = 0; d < 64; ++d) {
    float qv[4], kv[4];
#pragma unroll
    for (int i = 0; i < 4; ++i) { qv[i] = b2f(sQ[qb + i][d]); kv[i] = b2f(sK[kb + i][d]); }
#pragma unroll
    for (int i = 0; i < 4; ++i)
#pragma unroll
      for (int j = 0; j < 4; ++j) a[i][j] += qv[i] * kv[j];
  }
  for (int d = 0; d < 16; ++d) {
    float qv[4], kv[4];
#pragma unroll
    for (int i = 0; i < 4; ++i) { qv[i] = b2f(sCQ[qb + i][d]); kv[i] = b2f(sCK[kb + i][d]); }
#pragma unroll
    for (int i = 0; i < 4; ++i)
#pragma unroll
      for (int j = 0; j < 4; ++j) a[i][j] += qv[i] * kv[j];
  }
  const bool lastx = (wx == 15), lasty = (wy == 15);
#pragma unroll
  for (int i = 0; i < 4; ++i)
#pragma unroll
    for (int j = 0; j < 4; ++j) {
      int q = qb + i, k = kb + j;
      int qh = q >> 3, qw = q & 7, kh = k >> 3, kw = k & 7;
      bool msk = (lastx && ((qh >= 4) != (kh >= 4))) ||
                 (lasty && ((qw >= 4) != (kw >= 4)));
      // bias[q][k] = pos_emb[h_k - h_q + 7][w_k - w_q + 7]  (ri = idx[k]-idx[q])
      float bias = sPos[kh - qh + 7][kw - qw + 7];
      sS[q][k] = msk ? -1e30f : a[i][j] * SCALE_F + bias;
    }
  __syncthreads();
  if (t < 64) {
    float mx = -1e30f;
    for (int k = 0; k < 64; ++k) mx = fmaxf(mx, sS[t][k]);
    float sum = 0.f;
    for (int k = 0; k < 64; ++k) { float e = __expf(sS[t][k] - mx); sS[t][k] = e; sum += e; }
    float inv = 1.f / sum;
    for (int k = 0; k < 64; ++k) sS[t][k] *= inv;
  }
  __syncthreads();

  // PV: thread computes 4x4 tile of O (rows qb.., cols db..)
  const int db = (t & 15) << 2;
  float o[4][4] = {};
  for (int k = 0; k < 64; ++k) {
    float pv[4], vv[4];
#pragma unroll
    for (int i = 0; i < 4; ++i) { pv[i] = sS[qb + i][k]; vv[i] = b2f(sV[k][db + i]); }
#pragma unroll
    for (int i = 0; i < 4; ++i)
#pragma unroll
      for (int j = 0; j < 4; ++j) o[i][j] += pv[i] * vv[j];
  }
#pragma unroll
  for (int i = 0; i < 4; ++i) {
    int q = qb + i;
    const int y = ((wy << 3) + (q >> 3) + 4) & 127;
    const int x = ((wx << 3) + (q & 7) + 4) & 127;
    const size_t tok = ((size_t)b << 14) | (y << 7) | x;
    bf16* dst = aout + tok * 512 + head * 64 + db;
#pragma unroll
    for (int j = 0; j < 4; ++j) dst[j] = __float2bfloat16(o[i][j]);
  }
}

extern "C" void kernel_launch(void* const* d_in, const int* in_sizes, int n_in,
                              void* d_out, int out_size, void* d_ws, size_t ws_size,
                              hipStream_t stream) {
  const float* features = (const float*)d_in[0];
  const float* coords   = (const float*)d_in[1];
  const float* w_fqk = (const float*)d_in[2];
  const float* b_fqk = (const float*)d_in[3];
  const float* g_fqk = (const float*)d_in[4];
  const float* w_cqk = (const float*)d_in[5];
  const float* b_cqk = (const float*)d_in[6];
  const float* g_cqk = (const float*)d_in[7];
  const float* w_v   = (const float*)d_in[8];
  const float* b_v   = (const float*)d_in[9];
  const float* w_out = (const float*)d_in[10];
  const float* b_out = (const float*)d_in[11];
  const float* pos_emb = (const float*)d_in[12];
  float* out = (float*)d_out;   // reference output dtype is float32

  const int M = TOKENS;  // 65536
  bf16* fqk   = (bf16*)d_ws;                     // M*1024
  bf16* cqk   = fqk + (size_t)M * 1024;          // M*256
  bf16* fv    = cqk + (size_t)M * 256;           // M*512
  bf16* aout  = fv + (size_t)M * 512;            // M*512
  bf16* wfqkT = aout + (size_t)M * 512;          // 1024*512
  bf16* wcqkT = wfqkT + 1024 * 512;              // 256*128
  bf16* wvT   = wcqkT + 256 * 128;               // 512*512
  bf16* woutT = wvT + 512 * 512;                 // 512*512

  transpose_k<<<(512 * 1024 + 255) / 256, 256, 0, stream>>>(w_fqk, wfqkT, 512, 1024);
  transpose_k<<<(128 * 256 + 255) / 256, 256, 0, stream>>>(w_cqk, wcqkT, 128, 256);
  transpose_k<<<(512 * 512 + 255) / 256, 256, 0, stream>>>(w_v, wvT, 512, 512);
  transpose_k<<<(512 * 512 + 255) / 256, 256, 0, stream>>>(w_out, woutT, 512, 512);

  gemm_bias_k<float, bf16><<<dim3(1024 / 64, M / 64), 256, 0, stream>>>(features, wfqkT, b_fqk, fqk, M, 1024, 512);
  rmsnorm_k<<<M, 256, 0, stream>>>(fqk, g_fqk, 1024);
  gemm_bias_k<float, bf16><<<dim3(256 / 64, M / 64), 256, 0, stream>>>(coords, wcqkT, b_cqk, cqk, M, 256, 128);
  rmsnorm_k<<<M, 64, 0, stream>>>(cqk, g_cqk, 256);
  gemm_bias_k<float, bf16><<<dim3(512 / 64, M / 64), 256, 0, stream>>>(features, wvT, b_v, fv, M, 512, 512);
  attn_k<<<4 * 16 * 16 * 8, 256, 0, stream>>>(fqk, cqk, fv, pos_emb, aout);
  gemm_bias_k<bf16, float><<<dim3(512 / 64, M / 64), 256, 0, stream>>>(aout, woutT, b_out, out, M, 512, 512);
}

// Round 4
// 480.745 us; speedup vs baseline: 1.6865x; 1.6865x over previous
//
#include <hip/hip_runtime.h>
#include <hip/hip_bf16.h>
#include <type_traits>

using bf16 = __hip_bfloat16;
typedef __bf16 bf16x8 __attribute__((ext_vector_type(8)));
typedef float f32x4 __attribute__((ext_vector_type(4)));

static constexpr int TOKENS = 4 * 128 * 128;  // 65536
#define SCALE_F 0.11180339887498949f          // 1/sqrt(64+16)
#define EPS_F 1e-6f

__device__ __forceinline__ float u2f(unsigned short u) {
  union { unsigned int i; float f; } c; c.i = (unsigned int)u << 16; return c.f;
}
__device__ __forceinline__ unsigned short f2u(float f) {
  bf16 h = __float2bfloat16(f); return *reinterpret_cast<unsigned short*>(&h);
}
__device__ __forceinline__ float b2f(bf16 v) { return __bfloat162float(v); }
// load 8 f32, round to 8 bf16 packed in an int4
__device__ __forceinline__ int4 cvt8(const float* p) {
  float4 a = ((const float4*)p)[0], b = ((const float4*)p)[1];
  union { int4 i4; unsigned short s[8]; } u;
  u.s[0] = f2u(a.x); u.s[1] = f2u(a.y); u.s[2] = f2u(a.z); u.s[3] = f2u(a.w);
  u.s[4] = f2u(b.x); u.s[5] = f2u(b.y); u.s[6] = f2u(b.z); u.s[7] = f2u(b.w);
  return u.i4;
}
// async global->LDS, 16 bytes per lane (m97 mechanism)
__device__ __forceinline__ void gload16(const bf16* g, bf16* l) {
  __builtin_amdgcn_global_load_lds(
      (const __attribute__((address_space(1))) unsigned int*)g,
      (__attribute__((address_space(3))) unsigned int*)l, 16, 0, 0);
}

// ---------------- f32 -> bf16 bulk convert ----------------
__global__ void convert_k(const float* __restrict__ in, bf16* __restrict__ out,
                          long n) {
  long i = ((long)blockIdx.x * 256 + threadIdx.x) * 8;
  long stride = (long)gridDim.x * 256 * 8;
  for (; i < n; i += stride) *(int4*)(out + i) = cvt8(in + i);
}

// ---------------- weight transpose + f32->bf16: out[N][K] = in[K][N] ------
__global__ void transpose_k(const float* __restrict__ in, bf16* __restrict__ out,
                            int K, int N) {
  int i = blockIdx.x * 256 + threadIdx.x;
  if (i >= K * N) return;
  int k = i / N, n = i - k * N;
  out[(size_t)n * K + k] = __float2bfloat16(in[i]);
}

__global__ void biascat_k(const float* __restrict__ a, const float* __restrict__ b,
                          float* __restrict__ o) {
  int i = blockIdx.x * 256 + threadIdx.x;
  if (i < 1536) o[i] = i < 1024 ? a[i] : b[i - 1024];
}

// ---------------- GEMM (m97 structure): C[M,N] = A @ Wt^T + bias ----------
// BM=BN=128, BK=32, 256 threads (4 waves 2x2), global_load_lds width 16.
// A,Wt bf16; C bf16 or f32.
template <typename TC>
__global__ __launch_bounds__(256) void gemm128_k(
    const bf16* __restrict__ A, const bf16* __restrict__ Wt,
    const float* __restrict__ bias, TC* __restrict__ C,
    int M, int N, int K) {
  __shared__ __align__(16) bf16 sA[128 * 32];
  __shared__ __align__(16) bf16 sB[128 * 32];
  const int t = threadIdx.x, lane = t & 63, wave = t >> 6;
  const int wr = wave >> 1, wc = wave & 1;
  const int bm = blockIdx.y * 128, bn = blockIdx.x * 128;
  f32x4 acc[4][4] = {};

  const int srow = t >> 2;           // 0..63 (staging row within half-tile)
  const int ske = (t & 3) * 8;       // staging k-elem offset
  bf16* ldsA0 = sA + wave * 512;             // c=0 wave base
  bf16* ldsA1 = sA + 2048 + wave * 512;      // c=1
  bf16* ldsB0 = sB + wave * 512;
  bf16* ldsB1 = sB + 2048 + wave * 512;

  for (int k0 = 0; k0 < K; k0 += 32) {
    gload16(A + (size_t)(bm + srow) * K + k0 + ske, ldsA0);
    gload16(A + (size_t)(bm + 64 + srow) * K + k0 + ske, ldsA1);
    gload16(Wt + (size_t)(bn + srow) * K + k0 + ske, ldsB0);
    gload16(Wt + (size_t)(bn + 64 + srow) * K + k0 + ske, ldsB1);
    __syncthreads();
    bf16x8 af[4], bfr[4];
#pragma unroll
    for (int i = 0; i < 4; ++i) {
      int ar = wr * 64 + i * 16 + (lane & 15);
      int br = wc * 64 + i * 16 + (lane & 15);
      af[i]  = *(const bf16x8*)(sA + ar * 32 + (lane >> 4) * 8);
      bfr[i] = *(const bf16x8*)(sB + br * 32 + (lane >> 4) * 8);
    }
#pragma unroll
    for (int i = 0; i < 4; ++i)
#pragma unroll
      for (int j = 0; j < 4; ++j)
        acc[i][j] = __builtin_amdgcn_mfma_f32_16x16x32_bf16(af[i], bfr[j], acc[i][j], 0, 0, 0);
    __syncthreads();
  }
#pragma unroll
  for (int i = 0; i < 4; ++i)
#pragma unroll
    for (int j = 0; j < 4; ++j) {
      int col = bn + wc * 64 + j * 16 + (lane & 15);
      float bv = bias[col];
      int rbase = bm + wr * 64 + i * 16 + ((lane >> 4) << 2);
#pragma unroll
      for (int r = 0; r < 4; ++r) {
        float val = acc[i][j][r] + bv;
        if constexpr (std::is_same<TC, float>::value)
          C[(size_t)(rbase + r) * N + col] = val;
        else
          C[(size_t)(rbase + r) * N + col] = __float2bfloat16(val);
      }
    }
}

// ---------------- RMSNorm (in-place bf16, f32 gain, strided rows) ---------
__global__ void rmsnorm_k(bf16* __restrict__ x, const float* __restrict__ g,
                          int width, int stride) {
  const int t = threadIdx.x;
  bf16* p = x + (size_t)blockIdx.x * stride;
  ushort4 v = ((const ushort4*)p)[t];
  float f0 = u2f(v.x), f1 = u2f(v.y), f2 = u2f(v.z), f3 = u2f(v.w);
  float s = f0 * f0 + f1 * f1 + f2 * f2 + f3 * f3;
#pragma unroll
  for (int o = 32; o > 0; o >>= 1) s += __shfl_down(s, o);
  __shared__ float part[4];
  __shared__ float rsh;
  const int nw = blockDim.x >> 6;
  if ((t & 63) == 0) part[t >> 6] = s;
  __syncthreads();
  if (t == 0) {
    float tot = 0.f;
    for (int i = 0; i < nw; ++i) tot += part[i];
    rsh = rsqrtf(tot / (float)width + EPS_F);
  }
  __syncthreads();
  float r = rsh;
  float4 gv = ((const float4*)g)[t];
  ushort4 o;
  o.x = f2u(f0 * r * gv.x);
  o.y = f2u(f1 * r * gv.y);
  o.z = f2u(f2 * r * gv.z);
  o.w = f2u(f3 * r * gv.w);
  ((ushort4*)p)[t] = o;
}

// ---------------- MFMA windowed attention: one block per (window, head) ---
// qkv row layout: [0,512)=q, [512,1024)=k, [1024,1536)=v. cqk: [0,128)=cq,
// [128,256)=ck. Concatenate feat(64)+coord(16)+zeros(16) -> K=96 for S.
// 4 waves; wave w owns rows [w*16, w*16+16). Softmax in-register (16-lane
// shfl groups). P (unnormalized bf16) through LDS; V staged transposed.
__global__ __launch_bounds__(256) void attn_mfma_k(
    const bf16* __restrict__ qkv, const bf16* __restrict__ cqk,
    const float* __restrict__ pos, bf16* __restrict__ aout) {
  __shared__ __align__(16) bf16 sQ[64][104], sK[64][104];  // 96 used + pad
  __shared__ __align__(16) bf16 sVt[64][72];               // [d][kk]
  __shared__ __align__(16) bf16 sP[64][72];                // [q][kk]
  __shared__ float sPos[15][15];
  const int t = threadIdx.x, lane = t & 63, wave = t >> 6;
  const int head = blockIdx.x & 7;
  const int wid = blockIdx.x >> 3;
  const int wx = wid & 15, wy = (wid >> 4) & 15, b = wid >> 8;

  for (int i = t; i < 225; i += 256) sPos[i / 15][i % 15] = pos[i];
  {
    const int n = t >> 2, p = t & 3;
    const int y = ((wy << 3) + (n >> 3) + 4) & 127;
    const int x = ((wx << 3) + (n & 7) + 4) & 127;
    const size_t tok = ((size_t)b << 14) | (y << 7) | x;
    const bf16* row = qkv + tok * 1536;
    // Q, K: 16 elems each
    const int4* qp = (const int4*)(row + head * 64 + p * 16);
    ((int4*)&sQ[n][p * 16])[0] = qp[0];
    ((int4*)&sQ[n][p * 16])[1] = qp[1];
    const int4* kp = (const int4*)(row + 512 + head * 64 + p * 16);
    ((int4*)&sK[n][p * 16])[0] = kp[0];
    ((int4*)&sK[n][p * 16])[1] = kp[1];
    // V: 16 elems, transposed scatter
    const bf16* vp = row + 1024 + head * 64 + p * 16;
#pragma unroll
    for (int i = 0; i < 16; ++i) sVt[p * 16 + i][n] = vp[i];
    // coords + zero padding
    const bf16* crow = cqk + tok * 256;
    if (p == 0) {
      const int4* cp = (const int4*)(crow + head * 16);
      ((int4*)&sQ[n][64])[0] = cp[0];
      ((int4*)&sQ[n][64])[1] = cp[1];
    } else if (p == 1) {
      const int4* cp = (const int4*)(crow + 128 + head * 16);
      ((int4*)&sK[n][64])[0] = cp[0];
      ((int4*)&sK[n][64])[1] = cp[1];
    } else if (p == 2) {
      ((int4*)&sQ[n][80])[0] = int4{0, 0, 0, 0};
      ((int4*)&sQ[n][80])[1] = int4{0, 0, 0, 0};
    } else {
      ((int4*)&sK[n][80])[0] = int4{0, 0, 0, 0};
      ((int4*)&sK[n][80])[1] = int4{0, 0, 0, 0};
    }
  }
  __syncthreads();

  // ---- S = Q.K^T over K=96, rows w*16.. , 4 col-fragments ----
  const int l15 = lane & 15, kg = lane >> 4;
  bf16x8 qa[3];
#pragma unroll
  for (int ko = 0; ko < 3; ++ko)
    qa[ko] = *(const bf16x8*)&sQ[wave * 16 + l15][ko * 32 + kg * 8];
  f32x4 sacc[4] = {};
#pragma unroll
  for (int j = 0; j < 4; ++j)
#pragma unroll
    for (int ko = 0; ko < 3; ++ko) {
      bf16x8 kb = *(const bf16x8*)&sK[j * 16 + l15][ko * 32 + kg * 8];
      sacc[j] = __builtin_amdgcn_mfma_f32_16x16x32_bf16(qa[ko], kb, sacc[j], 0, 0, 0);
    }

  // ---- softmax in-register: rows w*16 + kg*4 + r, cols j*16 + l15 ----
  const bool lastx = (wx == 15), lasty = (wy == 15);
  float sv[4][4], mx[4], sum[4], inv[4];
#pragma unroll
  for (int r = 0; r < 4; ++r) mx[r] = -1e30f;
#pragma unroll
  for (int j = 0; j < 4; ++j) {
    int kcol = j * 16 + l15, kh = kcol >> 3, kw = kcol & 7;
#pragma unroll
    for (int r = 0; r < 4; ++r) {
      int q = wave * 16 + kg * 4 + r, qh = q >> 3, qw = q & 7;
      bool msk = (lastx && ((qh >= 4) != (kh >= 4))) ||
                 (lasty && ((qw >= 4) != (kw >= 4)));
      float val = msk ? -1e30f : sacc[j][r] * SCALE_F + sPos[kh - qh + 7][kw - qw + 7];
      sv[j][r] = val;
      mx[r] = fmaxf(mx[r], val);
    }
  }
#pragma unroll
  for (int m = 1; m < 16; m <<= 1)
#pragma unroll
    for (int r = 0; r < 4; ++r) mx[r] = fmaxf(mx[r], __shfl_xor(mx[r], m));
#pragma unroll
  for (int r = 0; r < 4; ++r) sum[r] = 0.f;
#pragma unroll
  for (int j = 0; j < 4; ++j) {
    int kcol = j * 16 + l15;
#pragma unroll
    for (int r = 0; r < 4; ++r) {
      float e = __expf(sv[j][r] - mx[r]);
      sum[r] += e;
      sP[wave * 16 + kg * 4 + r][kcol] = __float2bfloat16(e);
    }
  }
#pragma unroll
  for (int m = 1; m < 16; m <<= 1)
#pragma unroll
    for (int r = 0; r < 4; ++r) sum[r] += __shfl_xor(sum[r], m);
#pragma unroll
  for (int r = 0; r < 4; ++r) inv[r] = 1.f / sum[r];

  // ---- O = P.V (rows w*16..), V^T staged; scale by inv at epilogue ----
  bf16x8 pa[2];
#pragma unroll
  for (int ko = 0; ko < 2; ++ko)
    pa[ko] = *(const bf16x8*)&sP[wave * 16 + l15][ko * 32 + kg * 8];
  f32x4 oacc[4] = {};
#pragma unroll
  for (int jf = 0; jf < 4; ++jf)
#pragma unroll
    for (int ko = 0; ko < 2; ++ko) {
      bf16x8 vb = *(const bf16x8*)&sVt[jf * 16 + l15][ko * 32 + kg * 8];
      oacc[jf] = __builtin_amdgcn_mfma_f32_16x16x32_bf16(pa[ko], vb, oacc[jf], 0, 0, 0);
    }
#pragma unroll
  for (int r = 0; r < 4; ++r) {
    int q = wave * 16 + kg * 4 + r;
    const int y = ((wy << 3) + (q >> 3) + 4) & 127;
    const int x = ((wx << 3) + (q & 7) + 4) & 127;
    const size_t tok = ((size_t)b << 14) | (y << 7) | x;
    bf16* dst = aout + tok * 512 + head * 64;
#pragma unroll
    for (int jf = 0; jf < 4; ++jf)
      dst[jf * 16 + l15] = __float2bfloat16(oacc[jf][r] * inv[r]);
  }
}

extern "C" void kernel_launch(void* const* d_in, const int* in_sizes, int n_in,
                              void* d_out, int out_size, void* d_ws, size_t ws_size,
                              hipStream_t stream) {
  const float* features = (const float*)d_in[0];
  const float* coords   = (const float*)d_in[1];
  const float* w_fqk = (const float*)d_in[2];
  const float* b_fqk = (const float*)d_in[3];
  const float* g_fqk = (const float*)d_in[4];
  const float* w_cqk = (const float*)d_in[5];
  const float* b_cqk = (const float*)d_in[6];
  const float* g_cqk = (const float*)d_in[7];
  const float* w_v   = (const float*)d_in[8];
  const float* b_v   = (const float*)d_in[9];
  const float* w_out = (const float*)d_in[10];
  const float* b_out = (const float*)d_in[11];
  const float* pos_emb = (const float*)d_in[12];
  float* out = (float*)d_out;

  const int M = TOKENS;  // 65536
  // workspace layout (bf16 elems unless noted)
  bf16* qkv   = (bf16*)d_ws;                       // M*1536
  bf16* cqk   = qkv + (size_t)M * 1536;            // M*256
  bf16* aout  = cqk + (size_t)M * 256;             // M*512
  bf16* wcombT = aout + (size_t)M * 512;           // 1536*512
  bf16* wcqkT  = wcombT + (size_t)1536 * 512;      // 256*128
  bf16* woutT  = wcqkT + 256 * 128;                // 512*512
  float* bias_comb = (float*)(woutT + 512 * 512);  // 1536 f32
  // temp bf16 inputs aliased into d_out (dead until final GEMM writes it)
  bf16* fb16 = (bf16*)d_out;                       // M*512
  bf16* cb16 = fb16 + (size_t)M * 512;             // M*128

  convert_k<<<2048, 256, 0, stream>>>(features, fb16, (long)M * 512);
  convert_k<<<1024, 256, 0, stream>>>(coords, cb16, (long)M * 128);
  transpose_k<<<(512 * 1024 + 255) / 256, 256, 0, stream>>>(w_fqk, wcombT, 512, 1024);
  transpose_k<<<(512 * 512 + 255) / 256, 256, 0, stream>>>(w_v, wcombT + (size_t)1024 * 512, 512, 512);
  transpose_k<<<(128 * 256 + 255) / 256, 256, 0, stream>>>(w_cqk, wcqkT, 128, 256);
  transpose_k<<<(512 * 512 + 255) / 256, 256, 0, stream>>>(w_out, woutT, 512, 512);
  biascat_k<<<6, 256, 0, stream>>>(b_fqk, b_v, bias_comb);

  // fused qk+v projection: [M,512] x [1536,512]^T -> [M,1536]
  gemm128_k<bf16><<<dim3(1536 / 128, M / 128), 256, 0, stream>>>(fb16, wcombT, bias_comb, qkv, M, 1536, 512);
  rmsnorm_k<<<M, 256, 0, stream>>>(qkv, g_fqk, 1024, 1536);
  gemm128_k<bf16><<<dim3(256 / 128, M / 128), 256, 0, stream>>>(cb16, wcqkT, b_cqk, cqk, M, 256, 128);
  rmsnorm_k<<<M, 64, 0, stream>>>(cqk, g_cqk, 256, 256);
  attn_mfma_k<<<4 * 16 * 16 * 8, 256, 0, stream>>>(qkv, cqk, pos_emb, aout);
  gemm128_k<float><<<dim3(512 / 128, M / 128), 256, 0, stream>>>(aout, woutT, b_out, out, M, 512, 512);
}

// Round 5
// 415.446 us; speedup vs baseline: 1.9516x; 1.1572x over previous
//
#include <hip/hip_runtime.h>
#include <hip/hip_bf16.h>
#include <type_traits>

using bf16 = __hip_bfloat16;
typedef __bf16 bf16x8 __attribute__((ext_vector_type(8)));
typedef float f32x4 __attribute__((ext_vector_type(4)));

static constexpr int TOKENS = 4 * 128 * 128;  // 65536
#define SCALE_F 0.11180339887498949f          // 1/sqrt(64+16)
#define EPS_F 1e-6f

__device__ __forceinline__ float u2f(unsigned short u) {
  union { unsigned int i; float f; } c; c.i = (unsigned int)u << 16; return c.f;
}
__device__ __forceinline__ unsigned short f2u(float f) {
  bf16 h = __float2bfloat16(f); return *reinterpret_cast<unsigned short*>(&h);
}
__device__ __forceinline__ float b2f(bf16 v) { return __bfloat162float(v); }
// load 8 f32, round to 8 bf16 packed in an int4
__device__ __forceinline__ int4 cvt8(const float* p) {
  float4 a = ((const float4*)p)[0], b = ((const float4*)p)[1];
  union { int4 i4; unsigned short s[8]; } u;
  u.s[0] = f2u(a.x); u.s[1] = f2u(a.y); u.s[2] = f2u(a.z); u.s[3] = f2u(a.w);
  u.s[4] = f2u(b.x); u.s[5] = f2u(b.y); u.s[6] = f2u(b.z); u.s[7] = f2u(b.w);
  return u.i4;
}
// async global->LDS, 16 bytes per lane (m97 mechanism)
__device__ __forceinline__ void gload16(const bf16* g, bf16* l) {
  __builtin_amdgcn_global_load_lds(
      (const __attribute__((address_space(1))) unsigned int*)g,
      (__attribute__((address_space(3))) unsigned int*)l, 16, 0, 0);
}

// ---------------- f32 -> bf16 bulk convert ----------------
__global__ void convert_k(const float* __restrict__ in, bf16* __restrict__ out,
                          long n) {
  long i = ((long)blockIdx.x * 256 + threadIdx.x) * 8;
  long stride = (long)gridDim.x * 256 * 8;
  for (; i < n; i += stride) *(int4*)(out + i) = cvt8(in + i);
}

// ---------------- weight transpose + f32->bf16: out[N][K] = in[K][N] ------
__global__ void transpose_k(const float* __restrict__ in, bf16* __restrict__ out,
                            int K, int N) {
  int i = blockIdx.x * 256 + threadIdx.x;
  if (i >= K * N) return;
  int k = i / N, n = i - k * N;
  out[(size_t)n * K + k] = __float2bfloat16(in[i]);
}

__global__ void biascat_k(const float* __restrict__ a, const float* __restrict__ b,
                          float* __restrict__ o) {
  int i = blockIdx.x * 256 + threadIdx.x;
  if (i < 1536) o[i] = i < 1024 ? a[i] : b[i - 1024];
}

// ---------------- GEMM (m97 structure + T1 swizzle): C = A @ Wt^T + bias --
// BM=BN=128, BK=32, 4 waves 2x2, global_load_lds w16. SSNX>0: emit per-row
// partial sum-of-squares (deterministic slots) for the first SSNX x-tiles.
template <typename TC, int SSNX>
__global__ __launch_bounds__(256) void gemm128_k(
    const bf16* __restrict__ A, const bf16* __restrict__ Wt,
    const float* __restrict__ bias, TC* __restrict__ C,
    float* __restrict__ ssq, int M, int N, int K) {
  __shared__ __align__(16) bf16 sA[128 * 32];
  __shared__ __align__(16) bf16 sB[128 * 32];
  const int t = threadIdx.x, lane = t & 63, wave = t >> 6;
  const int wr = wave >> 1, wc = wave & 1;
  // T1: bijective chunked XCD swizzle (requires nwg % 8 == 0)
  const int nwg = gridDim.x * gridDim.y;
  int id = blockIdx.y * gridDim.x + blockIdx.x;
  if ((nwg & 7) == 0) id = (id & 7) * (nwg >> 3) + (id >> 3);
  const int bx = id % gridDim.x, by = id / gridDim.x;
  const int bm = by * 128, bn = bx * 128;
  f32x4 acc[4][4] = {};

  const int srow = t >> 2;           // 0..63 (staging row within half-tile)
  const int ske = (t & 3) * 8;       // staging k-elem offset
  bf16* ldsA0 = sA + wave * 512;
  bf16* ldsA1 = sA + 2048 + wave * 512;
  bf16* ldsB0 = sB + wave * 512;
  bf16* ldsB1 = sB + 2048 + wave * 512;
  const int l15 = lane & 15, kg = lane >> 4;
  float bvj[4];
#pragma unroll
  for (int j = 0; j < 4; ++j) bvj[j] = bias[bn + wc * 64 + j * 16 + l15];

  for (int k0 = 0; k0 < K; k0 += 32) {
    gload16(A + (size_t)(bm + srow) * K + k0 + ske, ldsA0);
    gload16(A + (size_t)(bm + 64 + srow) * K + k0 + ske, ldsA1);
    gload16(Wt + (size_t)(bn + srow) * K + k0 + ske, ldsB0);
    gload16(Wt + (size_t)(bn + 64 + srow) * K + k0 + ske, ldsB1);
    __syncthreads();
    bf16x8 af[4], bfr[4];
#pragma unroll
    for (int i = 0; i < 4; ++i) {
      int ar = wr * 64 + i * 16 + l15;
      int br = wc * 64 + i * 16 + l15;
      af[i]  = *(const bf16x8*)(sA + ar * 32 + kg * 8);
      bfr[i] = *(const bf16x8*)(sB + br * 32 + kg * 8);
    }
#pragma unroll
    for (int i = 0; i < 4; ++i)
#pragma unroll
      for (int j = 0; j < 4; ++j)
        acc[i][j] = __builtin_amdgcn_mfma_f32_16x16x32_bf16(af[i], bfr[j], acc[i][j], 0, 0, 0);
    __syncthreads();
  }
#pragma unroll
  for (int i = 0; i < 4; ++i)
#pragma unroll
    for (int j = 0; j < 4; ++j) {
      int col = bn + wc * 64 + j * 16 + l15;
      int rbase = bm + wr * 64 + i * 16 + kg * 4;
#pragma unroll
      for (int r = 0; r < 4; ++r) {
        float val = acc[i][j][r] + bvj[j];
        if constexpr (std::is_same<TC, float>::value)
          C[(size_t)(rbase + r) * N + col] = val;
        else
          C[(size_t)(rbase + r) * N + col] = __float2bfloat16(val);
      }
    }
  if constexpr (SSNX > 0) {
    if (bx < SSNX) {
#pragma unroll
      for (int i = 0; i < 4; ++i) {
        int rbase = bm + wr * 64 + i * 16 + kg * 4;
#pragma unroll
        for (int r = 0; r < 4; ++r) {
          float s = 0.f;
#pragma unroll
          for (int j = 0; j < 4; ++j) {
            float v = acc[i][j][r] + bvj[j];
            s += v * v;
          }
          s += __shfl_xor(s, 1); s += __shfl_xor(s, 2);
          s += __shfl_xor(s, 4); s += __shfl_xor(s, 8);
          if (l15 == 0)
            ssq[(size_t)(rbase + r) * (SSNX * 2) + bx * 2 + wc] = s;
        }
      }
    }
  }
}

// ---------------- finalize: partial sumsq -> per-token rsqrt scales -------
__global__ void finalize_rs_k(const float* __restrict__ pf,
                              const float* __restrict__ pc,
                              float* __restrict__ rsf, float* __restrict__ rsc) {
  int i = blockIdx.x * 256 + threadIdx.x;
  if (i >= TOKENS) return;
  float s = 0.f;
#pragma unroll
  for (int j = 0; j < 16; ++j) s += pf[(size_t)i * 16 + j];
  rsf[i] = rsqrtf(s * (1.f / 1024.f) + EPS_F);
  float c = 0.f;
#pragma unroll
  for (int j = 0; j < 4; ++j) c += pc[(size_t)i * 4 + j];
  rsc[i] = rsqrtf(c * (1.f / 256.f) + EPS_F);
}

// ---------------- MFMA windowed attention: one block per (window, head) ---
// qkv rows hold RAW q|k|v. Normalization applied here: K-side staged with
// G[d]=g_q[d]*g_k[d] folded in; S fragments scaled by rs_q*rs_k per part.
__global__ __launch_bounds__(256) void attn_mfma_k(
    const bf16* __restrict__ qkv, const bf16* __restrict__ cqk,
    const float* __restrict__ pos, const float* __restrict__ g_fqk,
    const float* __restrict__ g_cqk, const float* __restrict__ rs_f,
    const float* __restrict__ rs_c, bf16* __restrict__ aout) {
  __shared__ __align__(16) bf16 sQ[64][104], sK[64][104];  // 96 used + pad
  __shared__ __align__(16) bf16 sVt[64][72];               // [d][kk]
  __shared__ __align__(16) bf16 sP[64][72];                // [q][kk]
  __shared__ float sPos[15][15];
  __shared__ float sRsF[64], sRsC[64];
  const int t = threadIdx.x, lane = t & 63, wave = t >> 6;
  const int head = blockIdx.x & 7;
  const int wid = blockIdx.x >> 3;
  const int wx = wid & 15, wy = (wid >> 4) & 15, b = wid >> 8;

  for (int i = t; i < 225; i += 256) sPos[i / 15][i % 15] = pos[i];
  if (t < 64) {
    const int y = ((wy << 3) + (t >> 3) + 4) & 127;
    const int x = ((wx << 3) + (t & 7) + 4) & 127;
    const size_t tok = ((size_t)b << 14) | (y << 7) | x;
    sRsF[t] = rs_f[tok];
    sRsC[t] = rs_c[tok];
  }
  {
    const int n = t >> 2, p = t & 3;
    const int y = ((wy << 3) + (n >> 3) + 4) & 127;
    const int x = ((wx << 3) + (n & 7) + 4) & 127;
    const size_t tok = ((size_t)b << 14) | (y << 7) | x;
    const bf16* row = qkv + tok * 1536;
    // Q: raw copy (16 elems)
    const int4* qp = (const int4*)(row + head * 64 + p * 16);
    ((int4*)&sQ[n][p * 16])[0] = qp[0];
    ((int4*)&sQ[n][p * 16])[1] = qp[1];
    // K: multiply by G[d] = g_q[d]*g_k[d]
    {
      const bf16* kpp = row + 512 + head * 64 + p * 16;
      const float* gq = g_fqk + head * 64 + p * 16;
      const float* gk = g_fqk + 512 + head * 64 + p * 16;
      union { int4 v[2]; unsigned short s[16]; } kt;
#pragma unroll
      for (int i = 0; i < 16; ++i)
        kt.s[i] = f2u(b2f(kpp[i]) * gq[i] * gk[i]);
      ((int4*)&sK[n][p * 16])[0] = kt.v[0];
      ((int4*)&sK[n][p * 16])[1] = kt.v[1];
    }
    // V: transposed scatter
    const bf16* vp = row + 1024 + head * 64 + p * 16;
#pragma unroll
    for (int i = 0; i < 16; ++i) sVt[p * 16 + i][n] = vp[i];
    // coords + zero padding
    const bf16* crow = cqk + tok * 256;
    if (p == 0) {  // CQ raw
      const int4* cp = (const int4*)(crow + head * 16);
      ((int4*)&sQ[n][64])[0] = cp[0];
      ((int4*)&sQ[n][64])[1] = cp[1];
    } else if (p == 1) {  // CK * Gc
      const bf16* ckp = crow + 128 + head * 16;
      const float* gcq = g_cqk + head * 16;
      const float* gck = g_cqk + 128 + head * 16;
      union { int4 v[2]; unsigned short s[16]; } ct;
#pragma unroll
      for (int i = 0; i < 16; ++i)
        ct.s[i] = f2u(b2f(ckp[i]) * gcq[i] * gck[i]);
      ((int4*)&sK[n][64])[0] = ct.v[0];
      ((int4*)&sK[n][64])[1] = ct.v[1];
    } else if (p == 2) {
      ((int4*)&sQ[n][80])[0] = int4{0, 0, 0, 0};
      ((int4*)&sQ[n][80])[1] = int4{0, 0, 0, 0};
    } else {
      ((int4*)&sK[n][80])[0] = int4{0, 0, 0, 0};
      ((int4*)&sK[n][80])[1] = int4{0, 0, 0, 0};
    }
  }
  __syncthreads();

  // ---- S: feature part (K=64, 2 MFMAs) + coord part (K=32, 1 MFMA) ----
  const int l15 = lane & 15, kg = lane >> 4;
  bf16x8 qa[3];
#pragma unroll
  for (int ko = 0; ko < 3; ++ko)
    qa[ko] = *(const bf16x8*)&sQ[wave * 16 + l15][ko * 32 + kg * 8];
  f32x4 saccf[4] = {}, saccc[4] = {};
#pragma unroll
  for (int j = 0; j < 4; ++j) {
#pragma unroll
    for (int ko = 0; ko < 2; ++ko) {
      bf16x8 kb = *(const bf16x8*)&sK[j * 16 + l15][ko * 32 + kg * 8];
      saccf[j] = __builtin_amdgcn_mfma_f32_16x16x32_bf16(qa[ko], kb, saccf[j], 0, 0, 0);
    }
    bf16x8 kb2 = *(const bf16x8*)&sK[j * 16 + l15][64 + kg * 8];
    saccc[j] = __builtin_amdgcn_mfma_f32_16x16x32_bf16(qa[2], kb2, saccc[j], 0, 0, 0);
  }

  // ---- softmax in-register: rows wave*16 + kg*4 + r, cols j*16 + l15 ----
  const bool lastx = (wx == 15), lasty = (wy == 15);
  float rqf[4], rqc[4];
#pragma unroll
  for (int r = 0; r < 4; ++r) {
    rqf[r] = sRsF[wave * 16 + kg * 4 + r];
    rqc[r] = sRsC[wave * 16 + kg * 4 + r];
  }
  float sv[4][4], mx[4], sum[4], inv[4];
#pragma unroll
  for (int r = 0; r < 4; ++r) mx[r] = -1e30f;
#pragma unroll
  for (int j = 0; j < 4; ++j) {
    int kcol = j * 16 + l15, kh = kcol >> 3, kw = kcol & 7;
    float rkf = sRsF[kcol], rkc = sRsC[kcol];
#pragma unroll
    for (int r = 0; r < 4; ++r) {
      int q = wave * 16 + kg * 4 + r, qh = q >> 3, qw = q & 7;
      bool msk = (lastx && ((qh >= 4) != (kh >= 4))) ||
                 (lasty && ((qw >= 4) != (kw >= 4)));
      float raw = saccf[j][r] * rqf[r] * rkf + saccc[j][r] * rqc[r] * rkc;
      float val = msk ? -1e30f : raw * SCALE_F + sPos[kh - qh + 7][kw - qw + 7];
      sv[j][r] = val;
      mx[r] = fmaxf(mx[r], val);
    }
  }
#pragma unroll
  for (int m = 1; m < 16; m <<= 1)
#pragma unroll
    for (int r = 0; r < 4; ++r) mx[r] = fmaxf(mx[r], __shfl_xor(mx[r], m));
#pragma unroll
  for (int r = 0; r < 4; ++r) sum[r] = 0.f;
#pragma unroll
  for (int j = 0; j < 4; ++j) {
    int kcol = j * 16 + l15;
#pragma unroll
    for (int r = 0; r < 4; ++r) {
      float e = __expf(sv[j][r] - mx[r]);
      sum[r] += e;
      sP[wave * 16 + kg * 4 + r][kcol] = __float2bfloat16(e);
    }
  }
#pragma unroll
  for (int m = 1; m < 16; m <<= 1)
#pragma unroll
    for (int r = 0; r < 4; ++r) sum[r] += __shfl_xor(sum[r], m);
#pragma unroll
  for (int r = 0; r < 4; ++r) inv[r] = 1.f / sum[r];
  __syncthreads();

  // ---- O = P.V (rows wave*16..), V^T staged; scale by inv at epilogue ----
  bf16x8 pa[2];
#pragma unroll
  for (int ko = 0; ko < 2; ++ko)
    pa[ko] = *(const bf16x8*)&sP[wave * 16 + l15][ko * 32 + kg * 8];
  f32x4 oacc[4] = {};
#pragma unroll
  for (int jf = 0; jf < 4; ++jf)
#pragma unroll
    for (int ko = 0; ko < 2; ++ko) {
      bf16x8 vb = *(const bf16x8*)&sVt[jf * 16 + l15][ko * 32 + kg * 8];
      oacc[jf] = __builtin_amdgcn_mfma_f32_16x16x32_bf16(pa[ko], vb, oacc[jf], 0, 0, 0);
    }
#pragma unroll
  for (int r = 0; r < 4; ++r) {
    int q = wave * 16 + kg * 4 + r;
    const int y = ((wy << 3) + (q >> 3) + 4) & 127;
    const int x = ((wx << 3) + (q & 7) + 4) & 127;
    const size_t tok = ((size_t)b << 14) | (y << 7) | x;
    bf16* dst = aout + tok * 512 + head * 64;
#pragma unroll
    for (int jf = 0; jf < 4; ++jf)
      dst[jf * 16 + l15] = __float2bfloat16(oacc[jf][r] * inv[r]);
  }
}

extern "C" void kernel_launch(void* const* d_in, const int* in_sizes, int n_in,
                              void* d_out, int out_size, void* d_ws, size_t ws_size,
                              hipStream_t stream) {
  const float* features = (const float*)d_in[0];
  const float* coords   = (const float*)d_in[1];
  const float* w_fqk = (const float*)d_in[2];
  const float* b_fqk = (const float*)d_in[3];
  const float* g_fqk = (const float*)d_in[4];
  const float* w_cqk = (const float*)d_in[5];
  const float* b_cqk = (const float*)d_in[6];
  const float* g_cqk = (const float*)d_in[7];
  const float* w_v   = (const float*)d_in[8];
  const float* b_v   = (const float*)d_in[9];
  const float* w_out = (const float*)d_in[10];
  const float* b_out = (const float*)d_in[11];
  const float* pos_emb = (const float*)d_in[12];
  float* out = (float*)d_out;

  const int M = TOKENS;  // 65536
  // workspace layout
  bf16* qkv   = (bf16*)d_ws;                       // M*1536 (raw q|k|v)
  bf16* cqk   = qkv + (size_t)M * 1536;            // M*256 (raw cq|ck)
  bf16* aout  = cqk + (size_t)M * 256;             // M*512
  bf16* wcombT = aout + (size_t)M * 512;           // 1536*512
  bf16* wcqkT  = wcombT + (size_t)1536 * 512;      // 256*128
  bf16* woutT  = wcqkT + 256 * 128;                // 512*512
  float* bias_comb = (float*)(woutT + 512 * 512);  // 1536 f32
  float* ssq_f = bias_comb + 1536;                 // M*16 f32
  float* ssq_c = ssq_f + (size_t)M * 16;           // M*4 f32
  float* rs_f  = ssq_c + (size_t)M * 4;            // M f32
  float* rs_c  = rs_f + M;                         // M f32
  // temp bf16 inputs aliased into d_out (dead until final GEMM writes it)
  bf16* fb16 = (bf16*)d_out;                       // M*512
  bf16* cb16 = fb16 + (size_t)M * 512;             // M*128

  convert_k<<<2048, 256, 0, stream>>>(features, fb16, (long)M * 512);
  convert_k<<<1024, 256, 0, stream>>>(coords, cb16, (long)M * 128);
  transpose_k<<<(512 * 1024 + 255) / 256, 256, 0, stream>>>(w_fqk, wcombT, 512, 1024);
  transpose_k<<<(512 * 512 + 255) / 256, 256, 0, stream>>>(w_v, wcombT + (size_t)1024 * 512, 512, 512);
  transpose_k<<<(128 * 256 + 255) / 256, 256, 0, stream>>>(w_cqk, wcqkT, 128, 256);
  transpose_k<<<(512 * 512 + 255) / 256, 256, 0, stream>>>(w_out, woutT, 512, 512);
  biascat_k<<<6, 256, 0, stream>>>(b_fqk, b_v, bias_comb);

  // fused qk+v projection (+ per-token q|k sumsq partials)
  gemm128_k<bf16, 8><<<dim3(12, 512), 256, 0, stream>>>(fb16, wcombT, bias_comb, qkv, ssq_f, M, 1536, 512);
  // coord projection (+ sumsq partials over all 256 cols)
  gemm128_k<bf16, 2><<<dim3(2, 512), 256, 0, stream>>>(cb16, wcqkT, b_cqk, cqk, ssq_c, M, 256, 128);
  finalize_rs_k<<<TOKENS / 256, 256, 0, stream>>>(ssq_f, ssq_c, rs_f, rs_c);
  attn_mfma_k<<<4 * 16 * 16 * 8, 256, 0, stream>>>(qkv, cqk, pos_emb, g_fqk, g_cqk, rs_f, rs_c, aout);
  gemm128_k<float, 0><<<dim3(4, 512), 256, 0, stream>>>(aout, woutT, b_out, out, nullptr, M, 512, 512);
}